// Round 13
// baseline (6492.307 us; speedup 1.0000x reference)
//
#include <hip/hip_runtime.h>
#include <cstdint>
#include <cstddef>

#define BB   64
#define SEQL 512
#define INF  512
#define HID  1024
#define GG   4096   // 4*HID

#define MU_    0.9f
#define SSTEP_ 0.1f
#define BETA_  0.999f
#define EPS_   1e-16f
#define SCL    2048.0f
#define ISCL   (1.0f / 2048.0f)

#define NWG   64
#define NTHR  1024
#define WLDS  131072                     // W_hh f16 single-plane, frag order
#define RLDS  32768                      // reduce slots (hpk aliases its head)
#define SMEM_BYTES (WLDS + RLDS)         // 163840 = 160 KiB exactly

typedef unsigned short u16;
typedef unsigned int   u32;
typedef unsigned long long u64;
typedef _Float16 half8 __attribute__((ext_vector_type(8)));
typedef float f32x4 __attribute__((ext_vector_type(4)));
typedef u32 u32x4 __attribute__((ext_vector_type(4)));

__device__ __forceinline__ f32x4 mfma16(half8 a, half8 b, f32x4 c) {
  return __builtin_amdgcn_mfma_f32_16x16x32_f16(a, b, c, 0, 0, 0);
}
__device__ __forceinline__ void fsplit(float v, _Float16& hi, _Float16& lo) {
  hi = (_Float16)v;
  lo = (_Float16)((v - (float)hi) * SCL);
}
// device-coherent (cross-XCD) atomic ops for control & h stores (proven path)
__device__ __forceinline__ u32 coh_load32(const u32* p) {
  return __hip_atomic_load(p, __ATOMIC_RELAXED, __HIP_MEMORY_SCOPE_AGENT);
}
__device__ __forceinline__ void coh_store32(u32* p, u32 v) {
  __hip_atomic_store(p, v, __ATOMIC_RELAXED, __HIP_MEMORY_SCOPE_AGENT);
}
__device__ __forceinline__ void coh_store64(u64* p, u64 v) {
  __hip_atomic_store(p, v, __ATOMIC_RELAXED, __HIP_MEMORY_SCOPE_AGENT);
}

// 8 batched device-coherent 16B loads from base addr (+ kk*64B), one asm block.
#define GLD8(o0,o1,o2,o3,o4,o5,o6,o7,addr)                      \
  asm volatile(                                                 \
    "global_load_dwordx4 %0, %8, off sc0 sc1\n\t"               \
    "global_load_dwordx4 %1, %8, off offset:64 sc0 sc1\n\t"     \
    "global_load_dwordx4 %2, %8, off offset:128 sc0 sc1\n\t"    \
    "global_load_dwordx4 %3, %8, off offset:192 sc0 sc1\n\t"    \
    "global_load_dwordx4 %4, %8, off offset:256 sc0 sc1\n\t"    \
    "global_load_dwordx4 %5, %8, off offset:320 sc0 sc1\n\t"    \
    "global_load_dwordx4 %6, %8, off offset:384 sc0 sc1\n\t"    \
    "global_load_dwordx4 %7, %8, off offset:448 sc0 sc1"        \
    : "=&v"(o0), "=&v"(o1), "=&v"(o2), "=&v"(o3),               \
      "=&v"(o4), "=&v"(o5), "=&v"(o6), "=&v"(o7)                \
    : "v"(addr))

// MFMA cluster for one kk: h fragment x 4 rt weight tiles (gates 0..3).
#define HIMF(Hk, kk)                                                        \
  {                                                                         \
    half8 ah = __builtin_bit_cast(half8, Hk);                               \
    const _Float16* wb = Wf + (size_t)((kq * 8 + (kk)) * 4) * 512 + lane * 8;\
    a0 = mfma16(ah, *(const half8*)(wb), a0);                               \
    a1 = mfma16(ah, *(const half8*)(wb + 512), a1);                         \
    a2 = mfma16(ah, *(const half8*)(wb + 1024), a2);                        \
    a3 = mfma16(ah, *(const half8*)(wb + 1536), a3);                        \
  }

// ---- transpose + f16-split: src [R][C] f32 -> dhi/dlo [C][R] f16 ----
__global__ __launch_bounds__(256) void transpose_split(const float* __restrict__ src,
                                                       _Float16* __restrict__ dhi,
                                                       _Float16* __restrict__ dlo,
                                                       int R, int C) {
  __shared__ float tile[32][33];
  int c0 = blockIdx.x * 32, r0 = blockIdx.y * 32;
  int tx = threadIdx.x & 31, ty = threadIdx.x >> 5;
#pragma unroll
  for (int i = 0; i < 32; i += 8)
    tile[ty + i][tx] = src[(size_t)(r0 + ty + i) * C + (c0 + tx)];
  __syncthreads();
#pragma unroll
  for (int i = 0; i < 32; i += 8) {
    float v = tile[tx][ty + i];
    _Float16 hi, lo;
    fsplit(v, hi, lo);
    size_t o = (size_t)(c0 + ty + i) * R + (r0 + tx);
    dhi[o] = hi;
    dlo[o] = lo;
  }
}

// ---- pre-split x: f32 [B*S][IN] -> f16 [B*S][2][IN] (hi plane, lo plane) ----
__global__ __launch_bounds__(256) void split_x(const float* __restrict__ x,
                                               _Float16* __restrict__ xs) {
  size_t i = (size_t)blockIdx.x * 256 + threadIdx.x;   // one 8-elem chunk
  size_t e = i * 8;
  size_t r = e / INF, col = e % INF;
  f32x4 v0 = *(const f32x4*)(x + e);
  f32x4 v1 = *(const f32x4*)(x + e + 4);
  half8 hi, lo;
#pragma unroll
  for (int j = 0; j < 4; j++) {
    _Float16 h_, l_;
    fsplit(v0[j], h_, l_); hi[j] = h_; lo[j] = l_;
    fsplit(v1[j], h_, l_); hi[4 + j] = h_; lo[4 + j] = l_;
  }
  _Float16* dst = xs + r * 2 * INF + col;
  *(half8*)(dst) = hi;
  *(half8*)(dst + INF) = lo;
}

// ---- init running state (h -> single f16 plane) ----
__global__ __launch_bounds__(256) void init_state(const float* __restrict__ h0,
                                                  const float* __restrict__ c0,
                                                  const float* __restrict__ v0,
                                                  const float* __restrict__ m0,
                                                  float* __restrict__ co,
                                                  float* __restrict__ vo,
                                                  float* __restrict__ mo,
                                                  _Float16* __restrict__ hhi) {
  int i = blockIdx.x * 256 + threadIdx.x;
  if (i < BB * GG) { vo[i] = v0[i]; mo[i] = m0[i]; }
  if (i < BB * HID) {
    co[i] = c0[i];
    hhi[i] = (_Float16)h0[i];
  }
}

// ---- grad chunk GEMM (f16-split), XCD-partitioned N + t-streamed ----
// 1D grid T*32. Mapping: xcd=blk&7 owns a fixed 512-col weight slice (1 MiB,
// stays resident in that XCD's private 4 MiB L2 for the entire kernel);
// w=blk>>3: n0_local = w&3 (4 blocks of 128 cols), t = w>>2 (streamed).
// Weight LLC traffic: 4 GiB -> 8 MiB. Per-block math bit-identical to r12.
__global__ __launch_bounds__(256) void grad_gemm(const _Float16* __restrict__ xs, // [B*S][2][IN]
                                                 const _Float16* __restrict__ whi,
                                                 const _Float16* __restrict__ wlo,
                                                 const float* __restrict__ bih,
                                                 float* __restrict__ grad,  // [Tc][B][G]
                                                 int t0) {
  int i = blockIdx.x;
  int xcd = i & 7;
  int w = i >> 3;
  int n0 = (xcd * 4 + (w & 3)) * 128;
  int tloc = w >> 2;
  int wave = threadIdx.x >> 6, lane = threadIdx.x & 63;
  int l15 = lane & 15, lg = lane >> 4;
  int t = t0 + tloc;
  int b = 16 * wave + l15;
  const _Float16* xh = xs + ((size_t)b * SEQL + t) * 2 * INF + lg * 8;
  const _Float16* wh = whi + (size_t)(n0 + l15) * INF + lg * 8;
  const _Float16* wl = wlo + (size_t)(n0 + l15) * INF + lg * 8;

  f32x4 accM[8] = {};
  f32x4 accL[8] = {};
  for (int kk = 0; kk < INF; kk += 32) {
    half8 ah = *(const half8*)(xh + kk);
    half8 al = *(const half8*)(xh + INF + kk);
#pragma unroll
    for (int nt = 0; nt < 8; nt++) {
      half8 bh = *(const half8*)(wh + (size_t)nt * 16 * INF + kk);
      half8 bl = *(const half8*)(wl + (size_t)nt * 16 * INF + kk);
      accM[nt] = mfma16(ah, bh, accM[nt]);
      accL[nt] = mfma16(al, bh, accL[nt]);
      accL[nt] = mfma16(ah, bl, accL[nt]);
    }
  }
#pragma unroll
  for (int nt = 0; nt < 8; nt++) {
    int g = n0 + nt * 16 + l15;
    float bias = bih[g];
#pragma unroll
    for (int r = 0; r < 4; r++) {
      int bo = 16 * wave + lg * 4 + r;
      grad[((size_t)tloc * BB + bo) * GG + g] = accM[nt][r] + accL[nt][r] * ISCL + bias;
    }
  }
}

// ---- momentum/second-moment scan: grad -> u = v'/(sqrt(m')+eps), in place ----
__global__ __launch_bounds__(256) void scan_vm(float* __restrict__ grad,
                                               float* __restrict__ vst,
                                               float* __restrict__ mst,
                                               int T) {
  int i = blockIdx.x * 256 + threadIdx.x;
  float v = vst[i], m = mst[i];
  for (int tt = 0; tt < T; ++tt) {
    size_t o = (size_t)tt * (BB * GG) + i;
    float g = grad[o];
    v = MU_ * v + SSTEP_ * g;
    m = BETA_ * m + (1.0f - BETA_) * g * g;
    grad[o] = v / (sqrtf(m) + EPS_);
  }
  vst[i] = v;
  mst[i] = m;
}

// ---- persistent recurrent kernel (UNCHANGED from round 11 — proven) ----
__global__ __attribute__((amdgpu_flat_work_group_size(NTHR, NTHR),
                          amdgpu_waves_per_eu(4, 4))) void rnn_persist(
    const float* __restrict__ u,          // [T][B][G]
    const _Float16* __restrict__ whh_hi,  // [G][H] f16
    const float* __restrict__ bhh,
    _Float16* __restrict__ hA, _Float16* __restrict__ hB,
    float* __restrict__ lout, float* __restrict__ hout,
    float* __restrict__ cout, u32* __restrict__ flags, int t0, int T) {
  extern __shared__ char smem[];
  _Float16* Wf = (_Float16*)smem;                 // 128 KiB frag-order weights
  float* red = (float*)(smem + WLDS);             // [bt4][kqh2][rt4][col16][16]
  u16* hpk = (u16*)(smem + WLDS);                 // aliases red head (sync-guarded)

  int tid = threadIdx.x;
  int wave = tid >> 6, lane = tid & 63;
  int l15 = lane & 15, lg = lane >> 4;
  int bt = wave >> 2, kq = wave & 3;
  int nb = blockIdx.x;

  // ---- stage W_hh slice into LDS in fragment order ----
  for (int s = tid; s < 8192; s += NTHR) {
    int ln = s & 63, rest = s >> 6;
    int rt = rest & 3, kk = (rest >> 2) & 7, kq2 = rest >> 5;
    int grow = rt * HID + nb * 16 + (ln & 15);
    int k = kq2 * 256 + kk * 32 + (ln >> 4) * 8;
    *(half8*)(Wf + (size_t)s * 8) = *(const half8*)(whh_hi + (size_t)grow * HID + k);
  }

  // epilogue constants: thread = (batch bo, cell j), all 1024 threads
  int bo = tid >> 4, j = tid & 15;
  int en = nb * 16 + j;
  int within = bo & 15, btE = bo >> 4;
  int wsl = (((within >> 2) + j) & 3) * 4 + (within & 3);  // de-swizzle slot
  float bh_[4], creg, uv[4];
#pragma unroll
  for (int q = 0; q < 4; q++) bh_[q] = bhh[q * HID + en];
  creg = cout[(size_t)bo * HID + en];
#pragma unroll
  for (int q = 0; q < 4; q++)
    uv[q] = u[(size_t)bo * GG + q * HID + en];  // tt=0 prefetch
  // h fragment byte offset for this lane's GEMM A-row
  u64 hOffB = (u64)(((bt * 16 + l15) * HID + kq * 256 + lg * 8) * 2);
  u64 hAB = (u64)(uintptr_t)hA + hOffB;
  u64 hBB = (u64)(uintptr_t)hB + hOffB;
  // h store mapping (tid<256): batch row sb, u64 segment ss of 16 cells
  int sb = tid >> 2, ss = tid & 3;
  u64* stA = (u64*)(hA + (size_t)sb * HID + nb * 16) + ss;
  u64* stB = (u64*)(hB + (size_t)sb * HID + nb * 16) + ss;
  __syncthreads();

  for (int tt = 0; tt < T; ++tt) {
    int gt = t0 + tt;
    u64 rB = (gt & 1) ? hBB : hAB;

    // ---- batched coherent h loads: 8 dwordx4, one asm block ----
    u32x4 H0, H1, H2, H3, H4, H5, H6, H7;
    GLD8(H0, H1, H2, H3, H4, H5, H6, H7, rB);
    asm volatile("s_waitcnt vmcnt(0)" ::: "memory");   // h landed
    __builtin_amdgcn_sched_barrier(0);

    f32x4 a0 = {}, a1 = {}, a2 = {}, a3 = {};
    HIMF(H0, 0) HIMF(H1, 1) HIMF(H2, 2) HIMF(H3, 3)
    HIMF(H4, 4) HIMF(H5, 5) HIMF(H6, 6) HIMF(H7, 7)

    // ---- pairwise kq reduce in LDS, granule-rotation swizzled ----
    int kqh = kq >> 1;
    int p = (lg + l15) & 3;  // rotated granule slot
    int sB0 = (((bt * 2 + kqh) * 4 + 0) * 16 + l15) * 16 + p * 4;
    int sB1 = (((bt * 2 + kqh) * 4 + 1) * 16 + l15) * 16 + p * 4;
    int sB2 = (((bt * 2 + kqh) * 4 + 2) * 16 + l15) * 16 + p * 4;
    int sB3 = (((bt * 2 + kqh) * 4 + 3) * 16 + l15) * 16 + p * 4;
    if (kq & 1) {
      *(f32x4*)(red + sB0) = a0;
      *(f32x4*)(red + sB1) = a1;
      *(f32x4*)(red + sB2) = a2;
      *(f32x4*)(red + sB3) = a3;
    }
    __syncthreads();
    if (!(kq & 1)) {
      *(f32x4*)(red + sB0) = a0 + *(const f32x4*)(red + sB0);
      *(f32x4*)(red + sB1) = a1 + *(const f32x4*)(red + sB1);
      *(f32x4*)(red + sB2) = a2 + *(const f32x4*)(red + sB2);
      *(f32x4*)(red + sB3) = a3 + *(const f32x4*)(red + sB3);
    }
    // prefetch next step's u (overlaps)
    float uvN[4] = {};
    if (tt + 1 < T) {
#pragma unroll
      for (int q = 0; q < 4; q++)
        uvN[q] = u[((size_t)(tt + 1) * BB + bo) * GG + q * HID + en];
    }
    __syncthreads();

    // ---- epilogue: all 1024 threads; red reads -> sync -> hpk write (alias)
    float gate[4];
#pragma unroll
    for (int q = 0; q < 4; q++) {
      float rec = red[(((btE * 2 + 0) * 4 + q) * 16 + j) * 16 + wsl] +
                  red[(((btE * 2 + 1) * 4 + q) * 16 + j) * 16 + wsl];
      gate[q] = uv[q] + rec + bh_[q];
    }
    float ig = 1.0f / (1.0f + expf(-gate[0]));
    float fg = 1.0f / (1.0f + expf(-gate[1]));
    float gg = tanhf(gate[2]);
    float og = 1.0f / (1.0f + expf(-gate[3]));
    creg = creg * fg + ig * gg;
    float hh = og * tanhf(creg);
    __syncthreads();  // all red reads done before hpk (aliased) is written

    lout[((size_t)bo * SEQL + gt) * HID + en] = hh;
    hpk[bo * 16 + j] = __builtin_bit_cast(u16, (_Float16)hh);
    if (gt == SEQL - 1) hout[(size_t)bo * HID + en] = hh;
    if (tt == T - 1)    cout[(size_t)bo * HID + en] = creg;
#pragma unroll
    for (int q = 0; q < 4; q++) uv[q] = uvN[q];
    __syncthreads();  // h pack complete

    // ---- coherent h stores: 256 x u64 from packed LDS (proven path) ----
    if (tid < 256) {
      u64 val = *(const u64*)(hpk + sb * 16 + ss * 4);
      coh_store64((gt & 1) ? stA : stB, val);
    }

    if (tt + 1 < T) {
      asm volatile("s_waitcnt vmcnt(0)" ::: "memory");  // drain own stores
      __syncthreads();
      u32 target = (u32)(t0 + tt + 1);
      if (tid == 0) coh_store32(flags + nb * 32, target);
      if (wave == 0) {
        const u32* f0 = flags + lane * 32;
        while (!__all(coh_load32(f0) >= target))
          __builtin_amdgcn_s_sleep(1);
      }
      __syncthreads();
    }
  }
}

extern "C" void kernel_launch(void* const* d_in, const int* in_sizes, int n_in,
                              void* d_out, int out_size, void* d_ws, size_t ws_size,
                              hipStream_t stream) {
  const float* x   = (const float*)d_in[0];
  const float* wih = (const float*)d_in[1];
  const float* whh = (const float*)d_in[2];
  const float* bih = (const float*)d_in[3];
  const float* bhh = (const float*)d_in[4];
  const float* h0  = (const float*)d_in[5];
  const float* c0  = (const float*)d_in[6];
  const float* v0  = (const float*)d_in[7];
  const float* m0  = (const float*)d_in[8];

  float* out  = (float*)d_out;
  float* lout = out;
  float* hout = out + (size_t)BB * SEQL * HID;
  float* cout = hout + (size_t)BB * HID;   // running c
  float* vout = cout + (size_t)BB * HID;   // running v
  float* mout = vout + (size_t)BB * GG;    // running m

  char* ws = (char*)d_ws;
  size_t o = 0;
  _Float16* wih_hi = (_Float16*)(ws + o); o += (size_t)GG * INF * 2;
  _Float16* wih_lo = (_Float16*)(ws + o); o += (size_t)GG * INF * 2;
  _Float16* whh_hi = (_Float16*)(ws + o); o += (size_t)GG * HID * 2;
  _Float16* whh_lo = (_Float16*)(ws + o); o += (size_t)GG * HID * 2;  // unused by persist
  _Float16* xs     = (_Float16*)(ws + o); o += (size_t)BB * SEQL * 2 * INF * 2;  // 64 MiB
  _Float16* hA     = (_Float16*)(ws + o); o += (size_t)BB * HID * 2;
  _Float16* hB     = (_Float16*)(ws + o); o += (size_t)BB * HID * 2;
  o = (o + 255) & ~(size_t)255;
  u32* flags = (u32*)(ws + o); o += (size_t)NWG * 32 * 4;
  float* U = (float*)(ws + o);

  const size_t STEP_BYTES = (size_t)BB * GG * sizeof(float);
  size_t cap = (ws_size > o) ? (ws_size - o) / STEP_BYTES : 1;
  if (cap < 1) cap = 1;
  int Tc = (int)(cap < (size_t)SEQL ? cap : (size_t)SEQL);

  split_x<<<(BB * SEQL * INF / 8) / 256, 256, 0, stream>>>(x, xs);
  transpose_split<<<dim3(GG / 32, INF / 32), 256, 0, stream>>>(wih, wih_hi, wih_lo, INF, GG);
  transpose_split<<<dim3(GG / 32, HID / 32), 256, 0, stream>>>(whh, whh_hi, whh_lo, HID, GG);
  init_state<<<(BB * GG) / 256, 256, 0, stream>>>(h0, c0, v0, m0, cout, vout, mout, hA);
  hipMemsetAsync(flags, 0, (size_t)NWG * 32 * 4, stream);

  for (int t0 = 0; t0 < SEQL; t0 += Tc) {
    int T = (SEQL - t0 < Tc) ? (SEQL - t0) : Tc;
    grad_gemm<<<T * 32, 256, 0, stream>>>(xs, wih_hi, wih_lo, bih, U, t0);
    scan_vm<<<(BB * GG) / 256, 256, 0, stream>>>(U, vout, mout, T);
    rnn_persist<<<NWG, NTHR, SMEM_BYTES, stream>>>(
        U, whh_hi, bhh,
        hA, hB,
        lout, hout, cout, flags, t0, T);
  }
}

// Round 14
// 4584.669 us; speedup vs baseline: 1.4161x; 1.4161x over previous
//
#include <hip/hip_runtime.h>
#include <cstdint>
#include <cstddef>

#define BB   64
#define SEQL 512
#define INF  512
#define HID  1024
#define GG   4096   // 4*HID

#define MU_    0.9f
#define SSTEP_ 0.1f
#define BETA_  0.999f
#define EPS_   1e-16f
#define SCL    2048.0f
#define ISCL   (1.0f / 2048.0f)

#define NWGC  64                         // consumer wgs (recurrence)
#define NWGP  128                        // producer wgs (grad GEMM + vm scan)
#define NWG_TOT (NWGC + NWGP)            // 192 <= 256 CUs, all co-resident
#define NTHR  1024
#define WLDS  131072                     // W_hh f16 single-plane, frag order
#define RLDS  32768                      // reduce slots (hpk aliases its head)
#define SMEM_BYTES (WLDS + RLDS)         // 163840 = 160 KiB exactly

typedef unsigned short u16;
typedef unsigned int   u32;
typedef unsigned long long u64;
typedef _Float16 half8 __attribute__((ext_vector_type(8)));
typedef float f32x4 __attribute__((ext_vector_type(4)));
typedef u32 u32x4 __attribute__((ext_vector_type(4)));

__device__ __forceinline__ f32x4 mfma16(half8 a, half8 b, f32x4 c) {
  return __builtin_amdgcn_mfma_f32_16x16x32_f16(a, b, c, 0, 0, 0);
}
__device__ __forceinline__ void fsplit(float v, _Float16& hi, _Float16& lo) {
  hi = (_Float16)v;
  lo = (_Float16)((v - (float)hi) * SCL);
}
// device-coherent (cross-XCD) atomic ops (proven path)
__device__ __forceinline__ u32 coh_load32(const u32* p) {
  return __hip_atomic_load(p, __ATOMIC_RELAXED, __HIP_MEMORY_SCOPE_AGENT);
}
__device__ __forceinline__ void coh_store32(u32* p, u32 v) {
  __hip_atomic_store(p, v, __ATOMIC_RELAXED, __HIP_MEMORY_SCOPE_AGENT);
}
__device__ __forceinline__ void coh_store64(u64* p, u64 v) {
  __hip_atomic_store(p, v, __ATOMIC_RELAXED, __HIP_MEMORY_SCOPE_AGENT);
}
__device__ __forceinline__ void coh_storef(float* p, float v) {
  __hip_atomic_store(p, v, __ATOMIC_RELAXED, __HIP_MEMORY_SCOPE_AGENT);
}

// 8 batched device-coherent 16B loads from base addr (+ kk*64B), one asm block.
#define GLD8(o0,o1,o2,o3,o4,o5,o6,o7,addr)                      \
  asm volatile(                                                 \
    "global_load_dwordx4 %0, %8, off sc0 sc1\n\t"               \
    "global_load_dwordx4 %1, %8, off offset:64 sc0 sc1\n\t"     \
    "global_load_dwordx4 %2, %8, off offset:128 sc0 sc1\n\t"    \
    "global_load_dwordx4 %3, %8, off offset:192 sc0 sc1\n\t"    \
    "global_load_dwordx4 %4, %8, off offset:256 sc0 sc1\n\t"    \
    "global_load_dwordx4 %5, %8, off offset:320 sc0 sc1\n\t"    \
    "global_load_dwordx4 %6, %8, off offset:384 sc0 sc1\n\t"    \
    "global_load_dwordx4 %7, %8, off offset:448 sc0 sc1"        \
    : "=&v"(o0), "=&v"(o1), "=&v"(o2), "=&v"(o3),               \
      "=&v"(o4), "=&v"(o5), "=&v"(o6), "=&v"(o7)                \
    : "v"(addr))

// 4 batched coherent dword loads (u prefetch), one asm block.
#define GLDU4(d0,d1,d2,d3,a0,a1,a2,a3)                          \
  asm volatile(                                                 \
    "global_load_dword %0, %4, off sc0 sc1\n\t"                 \
    "global_load_dword %1, %5, off sc0 sc1\n\t"                 \
    "global_load_dword %2, %6, off sc0 sc1\n\t"                 \
    "global_load_dword %3, %7, off sc0 sc1"                     \
    : "=&v"(d0), "=&v"(d1), "=&v"(d2), "=&v"(d3)                \
    : "v"(a0), "v"(a1), "v"(a2), "v"(a3))

// MFMA cluster for one kk: h fragment x 4 rt weight tiles (gates 0..3).
#define HIMF(Hk, kk)                                                        \
  {                                                                         \
    half8 ah = __builtin_bit_cast(half8, Hk);                               \
    const _Float16* wb = Wf + (size_t)((kq * 8 + (kk)) * 4) * 512 + lane * 8;\
    a0 = mfma16(ah, *(const half8*)(wb), a0);                               \
    a1 = mfma16(ah, *(const half8*)(wb + 512), a1);                         \
    a2 = mfma16(ah, *(const half8*)(wb + 1024), a2);                        \
    a3 = mfma16(ah, *(const half8*)(wb + 1536), a3);                        \
  }

// ---- transpose + f16-split: src [R][C] f32 -> dhi/dlo [C][R] f16 ----
__global__ __launch_bounds__(256) void transpose_split(const float* __restrict__ src,
                                                       _Float16* __restrict__ dhi,
                                                       _Float16* __restrict__ dlo,
                                                       int R, int C) {
  __shared__ float tile[32][33];
  int c0 = blockIdx.x * 32, r0 = blockIdx.y * 32;
  int tx = threadIdx.x & 31, ty = threadIdx.x >> 5;
#pragma unroll
  for (int i = 0; i < 32; i += 8)
    tile[ty + i][tx] = src[(size_t)(r0 + ty + i) * C + (c0 + tx)];
  __syncthreads();
#pragma unroll
  for (int i = 0; i < 32; i += 8) {
    float v = tile[tx][ty + i];
    _Float16 hi, lo;
    fsplit(v, hi, lo);
    size_t o = (size_t)(c0 + ty + i) * R + (r0 + tx);
    dhi[o] = hi;
    dlo[o] = lo;
  }
}

// ---- pre-split x: f32 [B*S][IN] -> f16 [B*S][2][IN] (hi plane, lo plane) ----
__global__ __launch_bounds__(256) void split_x(const float* __restrict__ x,
                                               _Float16* __restrict__ xs) {
  size_t i = (size_t)blockIdx.x * 256 + threadIdx.x;   // one 8-elem chunk
  size_t e = i * 8;
  size_t r = e / INF, col = e % INF;
  f32x4 v0 = *(const f32x4*)(x + e);
  f32x4 v1 = *(const f32x4*)(x + e + 4);
  half8 hi, lo;
#pragma unroll
  for (int j = 0; j < 4; j++) {
    _Float16 h_, l_;
    fsplit(v0[j], h_, l_); hi[j] = h_; lo[j] = l_;
    fsplit(v1[j], h_, l_); hi[4 + j] = h_; lo[4 + j] = l_;
  }
  _Float16* dst = xs + r * 2 * INF + col;
  *(half8*)(dst) = hi;
  *(half8*)(dst + INF) = lo;
}

// ---- init running state (h -> single f16 plane) ----
__global__ __launch_bounds__(256) void init_state(const float* __restrict__ h0,
                                                  const float* __restrict__ c0,
                                                  const float* __restrict__ v0,
                                                  const float* __restrict__ m0,
                                                  float* __restrict__ co,
                                                  float* __restrict__ vo,
                                                  float* __restrict__ mo,
                                                  _Float16* __restrict__ hhi) {
  int i = blockIdx.x * 256 + threadIdx.x;
  if (i < BB * GG) { vo[i] = v0[i]; mo[i] = m0[i]; }
  if (i < BB * HID) {
    co[i] = c0[i];
    hhi[i] = (_Float16)h0[i];
  }
}

// ---- FUSED persistent kernel: 192 wgs x 1024 thr ----
// wgs 0..63  : consumers — r11 recurrence body (proven), u via coherent loads,
//              step barrier extended with a producer-flag poll (wave 1).
// wgs 64..191: producers — grad GEMM (f16-split, K-halved) + v/m scan for a
//              fixed 16b x 128g tile, t-sequential, v/m in registers. Each
//              producer is PINNED to one CU => its 256KiB weight slice stays
//              resident in that XCD's L2 (what r13's swizzle couldn't pin).
// u handoff: producer coh-stores u[t], sets own padded flag = t+1 (monotonic).
__global__ __attribute__((amdgpu_flat_work_group_size(NTHR, NTHR),
                          amdgpu_waves_per_eu(4, 4))) void rnn_fused(
    const _Float16* __restrict__ xs,      // [B*S][2][IN]
    const _Float16* __restrict__ whi,     // W_ih^T hi [G][IN]
    const _Float16* __restrict__ wlo,     // W_ih^T lo [G][IN]
    const float* __restrict__ bih,
    float* __restrict__ u,                // [T][B][G] produced in-kernel
    const _Float16* __restrict__ whh_hi,  // [G][H] f16
    const float* __restrict__ bhh,
    _Float16* __restrict__ hA, _Float16* __restrict__ hB,
    float* __restrict__ lout, float* __restrict__ hout,
    float* __restrict__ cout,             // running c
    float* __restrict__ vst, float* __restrict__ mst,  // running v,m (=vout,mout)
    u32* __restrict__ flags, int t0, int T) {
  extern __shared__ char smem[];
  int tid = threadIdx.x;
  int wave = tid >> 6, lane = tid & 63;
  int l15 = lane & 15, lg = lane >> 4;

  if (blockIdx.x < NWGC) {
    // ================= CONSUMER =================
    _Float16* Wf = (_Float16*)smem;               // 128 KiB frag-order weights
    float* red = (float*)(smem + WLDS);           // [bt4][kqh2][rt4][col16][16]
    u16* hpk = (u16*)(smem + WLDS);               // aliases red head (sync-guarded)
    int bt = wave >> 2, kq = wave & 3;
    int nb = blockIdx.x;

    // stage W_hh slice into LDS in fragment order
    for (int s = tid; s < 8192; s += NTHR) {
      int ln = s & 63, rest = s >> 6;
      int rt = rest & 3, kk = (rest >> 2) & 7, kq2 = rest >> 5;
      int grow = rt * HID + nb * 16 + (ln & 15);
      int k = kq2 * 256 + kk * 32 + (ln >> 4) * 8;
      *(half8*)(Wf + (size_t)s * 8) = *(const half8*)(whh_hi + (size_t)grow * HID + k);
    }

    // epilogue constants: thread = (batch bo, cell j)
    int bo = tid >> 4, j = tid & 15;
    int en = nb * 16 + j;
    int within = bo & 15, btE = bo >> 4;
    int wsl = (((within >> 2) + j) & 3) * 4 + (within & 3);  // de-swizzle slot
    float bh_[4], creg;
#pragma unroll
    for (int q = 0; q < 4; q++) bh_[q] = bhh[q * HID + en];
    creg = cout[(size_t)bo * HID + en];
    // h fragment byte offset for this lane's GEMM A-row
    u64 hOffB = (u64)(((bt * 16 + l15) * HID + kq * 256 + lg * 8) * 2);
    u64 hAB = (u64)(uintptr_t)hA + hOffB;
    u64 hBB = (u64)(uintptr_t)hB + hOffB;
    // h store mapping (tid<256)
    int sb = tid >> 2, ss = tid & 3;
    u64* stA = (u64*)(hA + (size_t)sb * HID + nb * 16) + ss;
    u64* stB = (u64*)(hB + (size_t)sb * HID + nb * 16) + ss;
    // per-thread u base address (q=0 gate)
    u64 ubT = (u64)(uintptr_t)u + (((size_t)bo * GG) + en) * 4;
    __syncthreads();

    // wait for producers: u[t0] and u[t0+1] (prefetched during step 0)
    if (wave == 0) {
      u32 tp = (u32)(t0 + (T < 2 ? T : 2));
      const u32* p0 = flags + (size_t)(NWGC + 2 * lane) * 32;
      while (!__all(coh_load32(p0) >= tp && coh_load32(p0 + 32) >= tp))
        __builtin_amdgcn_s_sleep(1);
    }
    __syncthreads();
    // coherent prefetch of u[t0]
    float uv0, uv1, uv2, uv3;
    GLDU4(uv0, uv1, uv2, uv3, ubT, ubT + 4096, ubT + 8192, ubT + 12288);
    asm volatile("s_waitcnt vmcnt(0)"
                 : "+v"(uv0), "+v"(uv1), "+v"(uv2), "+v"(uv3) :: "memory");
    float uv[4] = {uv0, uv1, uv2, uv3};

    for (int tt = 0; tt < T; ++tt) {
      int gt = t0 + tt;
      u64 rB = (gt & 1) ? hBB : hAB;

      u32x4 H0, H1, H2, H3, H4, H5, H6, H7;
      GLD8(H0, H1, H2, H3, H4, H5, H6, H7, rB);
      asm volatile("s_waitcnt vmcnt(0)" ::: "memory");   // h landed
      __builtin_amdgcn_sched_barrier(0);

      f32x4 a0 = {}, a1 = {}, a2 = {}, a3 = {};
      HIMF(H0, 0) HIMF(H1, 1) HIMF(H2, 2) HIMF(H3, 3)
      HIMF(H4, 4) HIMF(H5, 5) HIMF(H6, 6) HIMF(H7, 7)

      // pairwise kq reduce in LDS, granule-rotation swizzled
      int kqh = kq >> 1;
      int p = (lg + l15) & 3;
      int sB0 = (((bt * 2 + kqh) * 4 + 0) * 16 + l15) * 16 + p * 4;
      int sB1 = (((bt * 2 + kqh) * 4 + 1) * 16 + l15) * 16 + p * 4;
      int sB2 = (((bt * 2 + kqh) * 4 + 2) * 16 + l15) * 16 + p * 4;
      int sB3 = (((bt * 2 + kqh) * 4 + 3) * 16 + l15) * 16 + p * 4;
      if (kq & 1) {
        *(f32x4*)(red + sB0) = a0;
        *(f32x4*)(red + sB1) = a1;
        *(f32x4*)(red + sB2) = a2;
        *(f32x4*)(red + sB3) = a3;
      }
      __syncthreads();
      if (!(kq & 1)) {
        *(f32x4*)(red + sB0) = a0 + *(const f32x4*)(red + sB0);
        *(f32x4*)(red + sB1) = a1 + *(const f32x4*)(red + sB1);
        *(f32x4*)(red + sB2) = a2 + *(const f32x4*)(red + sB2);
        *(f32x4*)(red + sB3) = a3 + *(const f32x4*)(red + sB3);
      }
      // coherent prefetch of next step's u (consumed after barrier fence)
      float uvN0 = 0, uvN1 = 0, uvN2 = 0, uvN3 = 0;
      if (tt + 1 < T) {
        u64 ubn = ubT + ((u64)(tt + 1) * ((u64)BB * GG * 4));
        GLDU4(uvN0, uvN1, uvN2, uvN3, ubn, ubn + 4096, ubn + 8192, ubn + 12288);
      }
      __syncthreads();

      // epilogue: all 1024 threads
      float gate[4];
#pragma unroll
      for (int q = 0; q < 4; q++) {
        float rec = red[(((btE * 2 + 0) * 4 + q) * 16 + j) * 16 + wsl] +
                    red[(((btE * 2 + 1) * 4 + q) * 16 + j) * 16 + wsl];
        gate[q] = uv[q] + rec + bh_[q];
      }
      float ig = 1.0f / (1.0f + expf(-gate[0]));
      float fg = 1.0f / (1.0f + expf(-gate[1]));
      float gg = tanhf(gate[2]);
      float og = 1.0f / (1.0f + expf(-gate[3]));
      creg = creg * fg + ig * gg;
      float hh = og * tanhf(creg);
      __syncthreads();  // all red reads done before hpk (aliased) is written

      lout[((size_t)bo * SEQL + gt) * HID + en] = hh;
      hpk[bo * 16 + j] = __builtin_bit_cast(u16, (_Float16)hh);
      if (gt == SEQL - 1) hout[(size_t)bo * HID + en] = hh;
      if (tt == T - 1)    cout[(size_t)bo * HID + en] = creg;
      __syncthreads();  // h pack complete

      if (tid < 256) {
        u64 val = *(const u64*)(hpk + sb * 16 + ss * 4);
        coh_store64((gt & 1) ? stA : stB, val);
      }

      if (tt + 1 < T) {
        // drain h stores + uvN loads (dep-carried so uv copy can't hoist)
        asm volatile("s_waitcnt vmcnt(0)"
                     : "+v"(uvN0), "+v"(uvN1), "+v"(uvN2), "+v"(uvN3) :: "memory");
        __syncthreads();
        u32 target = (u32)(t0 + tt + 1);
        if (tid == 0) coh_store32(flags + (size_t)nb * 32, target);
        if (wave == 0) {
          const u32* f0 = flags + (size_t)lane * 32;
          while (!__all(coh_load32(f0) >= target))
            __builtin_amdgcn_s_sleep(1);
        } else if (wave == 1) {
          u32 t2 = (u32)(t0 + (tt + 3 < T ? tt + 3 : T));
          const u32* p0 = flags + (size_t)(NWGC + 2 * lane) * 32;
          while (!__all(coh_load32(p0) >= t2 && coh_load32(p0 + 32) >= t2))
            __builtin_amdgcn_s_sleep(1);
        }
        __syncthreads();
        uv[0] = uvN0; uv[1] = uvN1; uv[2] = uvN2; uv[3] = uvN3;
      }
    }
  } else {
    // ================= PRODUCER =================
    float* pred = (float*)smem;  // [kh2][nt8][col16][row16] f32 = 16 KiB
    int pid = blockIdx.x - NWGC;         // 0..127
    int btp = pid & 3;                   // b-tile: rows btp*16..+15
    int n0 = (pid >> 2) * 128;           // g-slab: 128 cols
    int nt = wave & 7, kh = wave >> 3;   // wave: col-group, K-half

    // wave GEMM pointers (constant across t)
    const _Float16* xa = xs + (size_t)(btp * 16 + l15) * SEQL * (2 * INF)
                            + kh * 256 + lg * 8;
    const _Float16* whp = whi + (size_t)(n0 + nt * 16 + l15) * INF + kh * 256 + lg * 8;
    const _Float16* wlp = wlo + (size_t)(n0 + nt * 16 + l15) * INF + kh * 256 + lg * 8;
    float* pp = pred + (((kh * 8 + nt) * 16 + l15) * 16 + lg * 4);

    // epilogue: thread owns (b_l, g_l) and (b_l, g_l+64); v,m in registers
    int b_l = tid >> 6, g_l = tid & 63;
    int bg = btp * 16 + b_l;
    int g0 = n0 + g_l, g1 = n0 + g_l + 64;
    size_t gi0 = (size_t)bg * GG + g0, gi1 = (size_t)bg * GG + g1;
    float vr0 = vst[gi0], vr1 = vst[gi1];
    float mr0 = mst[gi0], mr1 = mst[gi1];
    float bi0 = bih[g0], bi1 = bih[g1];
    int nt0 = g_l >> 4, c0i = g_l & 15;          // for g_l (cols 0..63 -> nt 0..3)
    int nt1 = (g_l + 64) >> 4, c1i = g_l & 15;   // for g_l+64 (nt 4..7)
    __syncthreads();

    for (int tt = 0; tt < T; ++tt) {
      const _Float16* xt = xa + (size_t)(t0 + tt) * (2 * INF);
      f32x4 aM = {}, aL = {};
#pragma unroll
      for (int kk = 0; kk < 256; kk += 32) {
        half8 ah = *(const half8*)(xt + kk);
        half8 al = *(const half8*)(xt + INF + kk);
        half8 bh = *(const half8*)(whp + kk);
        half8 bl = *(const half8*)(wlp + kk);
        aM = mfma16(ah, bh, aM);
        aL = mfma16(al, bh, aL);
        aL = mfma16(ah, bl, aL);
      }
      f32x4 cb;
#pragma unroll
      for (int i2 = 0; i2 < 4; ++i2) cb[i2] = aM[i2] + aL[i2] * ISCL;
      *(f32x4*)pp = cb;
      __syncthreads();

      // epilogue: reduce K-halves, bias, v/m scan, coherent u store
      float rec0 = pred[((0 + nt0) * 16 + c0i) * 16 + b_l] +
                   pred[((8 + nt0) * 16 + c0i) * 16 + b_l];
      float rec1 = pred[((0 + nt1) * 16 + c1i) * 16 + b_l] +
                   pred[((8 + nt1) * 16 + c1i) * 16 + b_l];
      float gr0 = rec0 + bi0, gr1 = rec1 + bi1;
      vr0 = MU_ * vr0 + SSTEP_ * gr0;
      mr0 = BETA_ * mr0 + (1.0f - BETA_) * gr0 * gr0;
      vr1 = MU_ * vr1 + SSTEP_ * gr1;
      mr1 = BETA_ * mr1 + (1.0f - BETA_) * gr1 * gr1;
      float* ub = u + ((size_t)tt * BB + bg) * GG;
      coh_storef(ub + g0, vr0 / (sqrtf(mr0) + EPS_));
      coh_storef(ub + g1, vr1 / (sqrtf(mr1) + EPS_));
      if (tt == T - 1) {
        vst[gi0] = vr0; vst[gi1] = vr1;
        mst[gi0] = mr0; mst[gi1] = mr1;
      }
      asm volatile("s_waitcnt vmcnt(0)" ::: "memory");  // u stores drained
      __syncthreads();                                  // whole wg done with t
      if (tid == 0)
        coh_store32(flags + (size_t)(NWGC + pid) * 32, (u32)(t0 + tt + 1));
    }
  }
}

extern "C" void kernel_launch(void* const* d_in, const int* in_sizes, int n_in,
                              void* d_out, int out_size, void* d_ws, size_t ws_size,
                              hipStream_t stream) {
  const float* x   = (const float*)d_in[0];
  const float* wih = (const float*)d_in[1];
  const float* whh = (const float*)d_in[2];
  const float* bih = (const float*)d_in[3];
  const float* bhh = (const float*)d_in[4];
  const float* h0  = (const float*)d_in[5];
  const float* c0  = (const float*)d_in[6];
  const float* v0  = (const float*)d_in[7];
  const float* m0  = (const float*)d_in[8];

  float* out  = (float*)d_out;
  float* lout = out;
  float* hout = out + (size_t)BB * SEQL * HID;
  float* cout = hout + (size_t)BB * HID;   // running c
  float* vout = cout + (size_t)BB * HID;   // running v
  float* mout = vout + (size_t)BB * GG;    // running m

  char* ws = (char*)d_ws;
  size_t o = 0;
  _Float16* wih_hi = (_Float16*)(ws + o); o += (size_t)GG * INF * 2;
  _Float16* wih_lo = (_Float16*)(ws + o); o += (size_t)GG * INF * 2;
  _Float16* whh_hi = (_Float16*)(ws + o); o += (size_t)GG * HID * 2;
  _Float16* whh_lo = (_Float16*)(ws + o); o += (size_t)GG * HID * 2;  // staging only
  _Float16* xs     = (_Float16*)(ws + o); o += (size_t)BB * SEQL * 2 * INF * 2;  // 64 MiB
  _Float16* hA     = (_Float16*)(ws + o); o += (size_t)BB * HID * 2;
  _Float16* hB     = (_Float16*)(ws + o); o += (size_t)BB * HID * 2;
  o = (o + 255) & ~(size_t)255;
  u32* flags = (u32*)(ws + o); o += (size_t)NWG_TOT * 32 * 4;
  float* U = (float*)(ws + o);

  const size_t STEP_BYTES = (size_t)BB * GG * sizeof(float);
  size_t cap = (ws_size > o) ? (ws_size - o) / STEP_BYTES : 1;
  if (cap < 1) cap = 1;
  int Tc = (int)(cap < (size_t)SEQL ? cap : (size_t)SEQL);

  split_x<<<(BB * SEQL * INF / 8) / 256, 256, 0, stream>>>(x, xs);
  transpose_split<<<dim3(GG / 32, INF / 32), 256, 0, stream>>>(wih, wih_hi, wih_lo, INF, GG);
  transpose_split<<<dim3(GG / 32, HID / 32), 256, 0, stream>>>(whh, whh_hi, whh_lo, HID, GG);
  init_state<<<(BB * GG) / 256, 256, 0, stream>>>(h0, c0, v0, m0, cout, vout, mout, hA);
  hipMemsetAsync(flags, 0, (size_t)NWG_TOT * 32 * 4, stream);

  for (int t0 = 0; t0 < SEQL; t0 += Tc) {
    int T = (SEQL - t0 < Tc) ? (SEQL - t0) : Tc;
    rnn_fused<<<NWG_TOT, NTHR, SMEM_BYTES, stream>>>(
        xs, wih_hi, wih_lo, bih, U, whh_hi, bhh,
        hA, hB, lout, hout, cout, vout, mout, flags, t0, T);
  }
}